// Round 10
// baseline (50.408 us; speedup 1.0000x reference)
//
#include <hip/hip_runtime.h>

#define N_TOK 262144
#define DDIM  256
#define CCLS  50001
#define ROW4  (DDIM / 4)              // 64 float4 per row = one per lane
#define TOTAL4 (CCLS * ROW4)          // 3,200,064 float4

// K1: build per-class linked lists (heads: 0 = empty, value = row+1) and
// scatter slot map (slot: 0 = absent, value = target-index+1). Duplicate
// target entries race on slotmap, but their mean rows are bitwise identical
// (same list traversal), so the output is deterministic.
__global__ void build_kernel(const int* __restrict__ trow,
                             const int* __restrict__ tgt, int n_tgt,
                             int* __restrict__ heads,
                             int* __restrict__ next,
                             int* __restrict__ slotmap) {
    const int i = blockIdx.x * blockDim.x + threadIdx.x;
    if (i < N_TOK) {
        const int t = trow[i];
        const int old = atomicExch(&heads[t], i + 1);
        next[i] = old;                        // coalesced 1 MB write
    }
    if (i < n_tgt) slotmap[tgt[i]] = i + 1;
}

// K2: ALL the random reads, isolated. One wave per target entry: chase the
// class's list, sum rows, write the mean to a compact staging buffer
// (coalesced 1 KB per wave). No streaming traffic competes with the random
// gathers in this phase.
__global__ __launch_bounds__(256)
void gather_kernel(const float* __restrict__ in,
                   const int* __restrict__ tgt, int n_tgt,
                   const int* __restrict__ heads,
                   const int* __restrict__ next,
                   float* __restrict__ mean_buf) {
    const int lane = threadIdx.x & 63;
    const int i = (blockIdx.x * 256 + threadIdx.x) >> 6;   // global wave id
    if (i >= n_tgt) return;

    const int c = tgt[i];
    int r = heads[c];
    if (r == 0) return;                       // count 0: merge keeps center

    float4 acc = {0.f, 0.f, 0.f, 0.f};
    int cnt = 0;
    while (r != 0) {
        const int row = r - 1;
        // row-data load is independent of the serial next[] chain
        const float4 v =
            reinterpret_cast<const float4*>(in)[(long long)row * ROW4 + lane];
        r = next[row];
        acc.x += v.x; acc.y += v.y; acc.z += v.z; acc.w += v.w;
        ++cnt;
    }
    const float s = 1.0f / (float)cnt;
    float4 m = {acc.x * s, acc.y * s, acc.z * s, acc.w * s};
    reinterpret_cast<float4*>(mean_buf)[(long long)i * ROW4 + lane] = m;
}

// K3: pure streaming merge. Canonical one-thread-one-float4; per-row source
// select (mean_buf slot vs center). slotmap/heads loads are wave-broadcast
// (all 64 lanes read the same dword). No random traffic.
__global__ __launch_bounds__(256)
void merge_kernel(const float4* __restrict__ center,
                  const float4* __restrict__ mean_buf,
                  const int* __restrict__ heads,
                  const int* __restrict__ slotmap,
                  float4* __restrict__ out) {
    const int j = blockIdx.x * 256 + threadIdx.x;
    if (j >= TOTAL4) return;
    const int r = j >> 6;                     // class row (uniform per wave)
    const int o = j & 63;                     // float4 within row
    const int s = slotmap[r];
    const bool upd = (s > 0) && (heads[r] != 0);
    const float4* __restrict__ src =
        upd ? mean_buf + (long long)(s - 1) * ROW4
            : center + (long long)r * ROW4;
    out[j] = src[o];
}

extern "C" void kernel_launch(void* const* d_in, const int* in_sizes, int n_in,
                              void* d_out, int out_size, void* d_ws, size_t ws_size,
                              hipStream_t stream) {
    const float* inputs_row = (const float*)d_in[0];
    const float* center     = (const float*)d_in[1];
    const int*   target_row = (const int*)d_in[2];
    const int*   target     = (const int*)d_in[3];
    const int    n_target   = in_sizes[3];

    float* out = (float*)d_out;

    // ws layout: heads[CCLS] | slotmap[CCLS] | next[N_TOK] | mean_buf[4096*DDIM]
    int* heads    = (int*)d_ws;
    int* slotmap  = heads + CCLS;
    int* next     = slotmap + CCLS;
    float* mean_buf = (float*)(next + N_TOK);

    // heads = 0 (empty), slotmap = 0 (absent) in one 400 KB memset.
    hipMemsetAsync(heads, 0, (size_t)2 * CCLS * sizeof(int), stream);

    build_kernel<<<(N_TOK + 255) / 256, 256, 0, stream>>>(target_row, target,
                                                          n_target, heads, next,
                                                          slotmap);

    gather_kernel<<<(n_target * 64 + 255) / 256, 256, 0, stream>>>(
        inputs_row, target, n_target, heads, next, mean_buf);

    merge_kernel<<<(TOTAL4 + 255) / 256, 256, 0, stream>>>(
        reinterpret_cast<const float4*>(center),
        reinterpret_cast<const float4*>(mean_buf),
        heads, slotmap, reinterpret_cast<float4*>(out));
}

// Round 11
// 48.101 us; speedup vs baseline: 1.0480x; 1.0480x over previous
//
#include <hip/hip_runtime.h>

#define N_TOK 262144
#define DDIM  256
#define CCLS  50001
#define ROW4  (DDIM / 4)              // 64 float4 per row = one per lane
#define OUT_BLKS  1024
#define OUT_WAVES (OUT_BLKS * 4)      // 4096 persistent waves, ~12 rows each

// K1: heads = -1, present = 0.
__global__ void init_kernel(int* __restrict__ heads, int* __restrict__ present) {
    int i = blockIdx.x * blockDim.x + threadIdx.x;
    if (i < CCLS) {
        heads[i] = -1;
        present[i] = 0;
    }
}

// K2: build per-class linked lists over all rows + scatter present flags.
__global__ void build_kernel(const int* __restrict__ trow,
                             const int* __restrict__ tgt, int n_tgt,
                             int* __restrict__ heads,
                             int* __restrict__ next,
                             int* __restrict__ present) {
    int i = blockIdx.x * blockDim.x + threadIdx.x;
    if (i < N_TOK) {
        const int t = trow[i];
        const int old = atomicExch(&heads[t], i);
        next[i] = old;                    // coalesced 1 MB write
    }
    if (i < n_tgt) present[tgt[i]] = 1;   // benign race: all store 1
}

// K3: grid-stride persistent waves, one row per iteration.
// Non-updated row: copy center->out (1 KB coalesced per wave).
// Updated row: chase the list, sum rows in registers, write the mean.
__global__ __launch_bounds__(256)
void out_kernel(const float* __restrict__ in,
                const float* __restrict__ center,
                const int* __restrict__ heads,
                const int* __restrict__ next,
                const int* __restrict__ present,
                float* __restrict__ out) {
    const int lane = threadIdx.x & 63;
    const int gw = (blockIdx.x * 256 + threadIdx.x) >> 6;   // global wave id

    const float4* __restrict__ cen4 = reinterpret_cast<const float4*>(center);
    const float4* __restrict__ in4  = reinterpret_cast<const float4*>(in);
    float4* __restrict__ out4 = reinterpret_cast<float4*>(out);

    for (int r = gw; r < CCLS; r += OUT_WAVES) {
        const int head = heads[r];                          // broadcast load
        const bool upd = (present[r] != 0) && (head != -1);
        const long long o4 = (long long)r * ROW4 + lane;
        if (!upd) {
            out4[o4] = cen4[o4];
        } else {
            float4 acc = {0.f, 0.f, 0.f, 0.f};
            int cnt = 0;
            int row = head;
            while (row != -1) {
                const float4 v = in4[(long long)row * ROW4 + lane];
                row = next[row];            // chase overlaps row-data load
                acc.x += v.x; acc.y += v.y; acc.z += v.z; acc.w += v.w;
                ++cnt;
            }
            const float s = 1.0f / (float)cnt;
            float4 m = {acc.x * s, acc.y * s, acc.z * s, acc.w * s};
            out4[o4] = m;
        }
    }
}

extern "C" void kernel_launch(void* const* d_in, const int* in_sizes, int n_in,
                              void* d_out, int out_size, void* d_ws, size_t ws_size,
                              hipStream_t stream) {
    const float* inputs_row = (const float*)d_in[0];
    const float* center     = (const float*)d_in[1];
    const int*   target_row = (const int*)d_in[2];
    const int*   target     = (const int*)d_in[3];
    const int    n_target   = in_sizes[3];

    float* out = (float*)d_out;

    // ws layout (ints): heads[CCLS] | present[CCLS] | next[N_TOK]
    int* heads   = (int*)d_ws;
    int* present = heads + CCLS;
    int* next    = present + CCLS;

    init_kernel<<<(CCLS + 255) / 256, 256, 0, stream>>>(heads, present);
    build_kernel<<<(N_TOK + 255) / 256, 256, 0, stream>>>(target_row, target, n_target,
                                                          heads, next, present);
    out_kernel<<<OUT_BLKS, 256, 0, stream>>>(inputs_row, center, heads, next,
                                             present, out);
}